// Round 1
// baseline (63.460 us; speedup 1.0000x reference)
//
#include <hip/hip_runtime.h>

// Scalar vector-quantize (dim=1, K=64): out[i] = codebook[argmin_k (w[i]-c[k])^2]
// Exact replication of numpy semantics: d = fl(w - c); d2 = fl(d*d);
// ascending-k strict-< update == argmin first-index tie-break.
// We track the winning VALUE (what the output needs), not the index.

#define VQ_K 64

__global__ __launch_bounds__(256) void vq_naive_kernel(
    const float* __restrict__ w,
    const float* __restrict__ cb,
    float* __restrict__ out,
    int n4)   // number of float4 groups
{
    int i = blockIdx.x * blockDim.x + threadIdx.x;
    if (i >= n4) return;

    const float4 wv = reinterpret_cast<const float4*>(w)[i];
    float wx[4] = {wv.x, wv.y, wv.z, wv.w};
    float bd[4], bv[4];

    // k = 0 init
    {
        const float c0 = cb[0];
#pragma unroll
        for (int j = 0; j < 4; ++j) {
            float d = wx[j] - c0;
            bd[j] = d * d;
            bv[j] = c0;
        }
    }

#pragma unroll
    for (int k = 1; k < VQ_K; ++k) {
        const float c = cb[k];   // uniform address -> scalar load (SGPR)
#pragma unroll
        for (int j = 0; j < 4; ++j) {
            float d  = wx[j] - c;
            float dd = d * d;
            bool lt  = dd < bd[j];
            bd[j] = lt ? dd : bd[j];
            bv[j] = lt ? c  : bv[j];
        }
    }

    float4 o;
    o.x = bv[0]; o.y = bv[1]; o.z = bv[2]; o.w = bv[3];
    reinterpret_cast<float4*>(out)[i] = o;
}

// Scalar tail (n not divisible by 4) — N=8388608 is divisible, but be safe.
__global__ void vq_tail_kernel(
    const float* __restrict__ w,
    const float* __restrict__ cb,
    float* __restrict__ out,
    int start, int n)
{
    int i = start + blockIdx.x * blockDim.x + threadIdx.x;
    if (i >= n) return;
    float wx = w[i];
    float c0 = cb[0];
    float d0 = wx - c0;
    float bd = d0 * d0;
    float bv = c0;
#pragma unroll
    for (int k = 1; k < VQ_K; ++k) {
        float c  = cb[k];
        float d  = wx - c;
        float dd = d * d;
        bool lt  = dd < bd;
        bd = lt ? dd : bd;
        bv = lt ? c  : bv;
    }
    out[i] = bv;
}

extern "C" void kernel_launch(void* const* d_in, const int* in_sizes, int n_in,
                              void* d_out, int out_size, void* d_ws, size_t ws_size,
                              hipStream_t stream) {
    const float* w  = (const float*)d_in[0];
    const float* cb = (const float*)d_in[1];
    float* out = (float*)d_out;
    const int n  = in_sizes[0];
    const int n4 = n / 4;

    if (n4 > 0) {
        const int block = 256;
        const int grid  = (n4 + block - 1) / block;
        vq_naive_kernel<<<grid, block, 0, stream>>>(w, cb, out, n4);
    }
    const int tail_start = n4 * 4;
    const int tail = n - tail_start;
    if (tail > 0) {
        vq_tail_kernel<<<1, 64, 0, stream>>>(w, cb, out, tail_start, n);
    }
}

// Round 2
// 22.387 us; speedup vs baseline: 2.8347x; 2.8347x over previous
//
#include <hip/hip_runtime.h>

// Scalar VQ (dim=1, K=64) via sorted-codebook binary search.
// Exactness: float compares are exact; fl(w-c) and fl(d*d) are monotone in
// |w-c|, so the argmin of fl-distance over all 64 codes is attained at one of
// the two sorted neighbors bracketing w. We compare those two with the exact
// reference arithmetic (d = fl(w-c); d2 = fl(d*d)); on an exact fl-tie we
// compare ORIGINAL indices (numpy argmin first-index rule). Padded sentinels
// (+inf) at both ends make the bracketing branch-free.

#define VQ_K   64
#define NPAD   66      // [0]=+inf, [1..64]=sorted, [65]=+inf
#define TPB    256
#define EPT    8       // elements per thread (two float4)

__global__ void vq_prep_kernel(const float* __restrict__ cb,
                               float* __restrict__ S, int* __restrict__ SI) {
    int t = threadIdx.x;
    if (t < VQ_K) {
        float c = cb[t];
        int rank = 0;
#pragma unroll
        for (int j = 0; j < VQ_K; ++j) {
            float cj = cb[j];
            rank += (cj < c || (cj == c && j < t)) ? 1 : 0;  // stable rank
        }
        S[rank + 1]  = c;
        SI[rank + 1] = t;
    }
    if (t == 0) {
        S[0]          = __builtin_inff(); SI[0]          = 1 << 30;
        S[VQ_K + 1]   = __builtin_inff(); SI[VQ_K + 1]   = 1 << 30;
    }
}

__global__ __launch_bounds__(TPB) void vq_search_kernel(
    const float* __restrict__ w,
    const float* __restrict__ Sg,
    const int*  __restrict__ SIg,
    float* __restrict__ out,
    int n_thr)   // number of EPT-element thread slots
{
    __shared__ float S[NPAD];
    __shared__ int   SI[NPAD];
    const int tid = threadIdx.x;
    if (tid < NPAD) { S[tid] = Sg[tid]; SI[tid] = SIg[tid]; }
    __syncthreads();

    // Hoist top 3 tree levels into registers (uniform values).
    const float c32 = S[32];                    // pivot, level s=32
    const float c16 = S[16], c48 = S[48];       // level s=16
    const float c8  = S[8],  c24 = S[24];       // level s=8
    const float c40 = S[40], c56 = S[56];

    const int t = blockIdx.x * TPB + tid;
    if (t >= n_thr) return;
    const long base = (long)t * EPT;

    const float4* wv4 = reinterpret_cast<const float4*>(w + base);
    float4 a = wv4[0], b = wv4[1];
    float x[EPT] = {a.x, a.y, a.z, a.w, b.x, b.y, b.z, b.w};
    float r[EPT];

#pragma unroll
    for (int e = 0; e < EPT; ++e) {
        const float wv = x[e];
        // pos = min(#codes <= wv, 63); candidates are padded S[pos], S[pos+1]
        bool b0 = (c32 <= wv); int pos = b0 ? 32 : 0;
        float p1 = b0 ? c48 : c16;
        bool b1 = (p1 <= wv); pos += b1 ? 16 : 0;
        float pa = b0 ? c56 : c24, pb = b0 ? c40 : c8;
        float p2 = b1 ? pa : pb;
        bool b2 = (p2 <= wv); pos += b2 ? 8 : 0;
        pos += (S[pos + 4] <= wv) ? 4 : 0;
        pos += (S[pos + 2] <= wv) ? 2 : 0;
        pos += (S[pos + 1] <= wv) ? 1 : 0;

        const float cl = S[pos], cr = S[pos + 1];
        const float dl = wv - cl, dr = wv - cr;
        const float dl2 = dl * dl, dr2 = dr * dr;
        float q = (dr2 < dl2) ? cr : cl;
        if (dl2 == dr2) {                 // exact fl-tie: numpy first-index rule
            q = (SI[pos] < SI[pos + 1]) ? cl : cr;
        }
        r[e] = q;
    }

    float4* o4 = reinterpret_cast<float4*>(out + base);
    o4[0] = make_float4(r[0], r[1], r[2], r[3]);
    o4[1] = make_float4(r[4], r[5], r[6], r[7]);
}

// Naive exact fallback for tail elements (n % EPT != 0).
__global__ void vq_tail_kernel(const float* __restrict__ w,
                               const float* __restrict__ cb,
                               float* __restrict__ out, int start, int n) {
    int i = start + blockIdx.x * blockDim.x + threadIdx.x;
    if (i >= n) return;
    float wx = w[i];
    float c0 = cb[0], d0 = wx - c0;
    float bd = d0 * d0, bv = c0;
#pragma unroll
    for (int k = 1; k < VQ_K; ++k) {
        float c = cb[k], d = wx - c, dd = d * d;
        bool lt = dd < bd;
        bd = lt ? dd : bd;
        bv = lt ? c : bv;
    }
    out[i] = bv;
}

extern "C" void kernel_launch(void* const* d_in, const int* in_sizes, int n_in,
                              void* d_out, int out_size, void* d_ws, size_t ws_size,
                              hipStream_t stream) {
    const float* w  = (const float*)d_in[0];
    const float* cb = (const float*)d_in[1];
    float* out = (float*)d_out;
    const int n = in_sizes[0];

    float* S  = (float*)d_ws;                 // NPAD floats
    int*   SI = (int*)((char*)d_ws + NPAD * sizeof(float));

    vq_prep_kernel<<<1, 64, 0, stream>>>(cb, S, SI);

    const int n_main = (n / EPT) * EPT;
    const int n_thr  = n_main / EPT;
    if (n_thr > 0) {
        const int grid = (n_thr + TPB - 1) / TPB;
        vq_search_kernel<<<grid, TPB, 0, stream>>>(w, S, SI, out, n_thr);
    }
    if (n_main < n) {
        vq_tail_kernel<<<1, 64, 0, stream>>>(w, cb, out, n_main, n);
    }
}

// Round 3
// 21.983 us; speedup vs baseline: 2.8868x; 1.0184x over previous
//
#include <hip/hip_runtime.h>

// Scalar VQ (dim=1, K=64), single fused kernel.
// Each block sorts the codebook into LDS (rank sort), builds replicated
// per-level pivot tables, then each thread binary-searches 16 elements.
// Exactness: fl(w-c) and fl(d*d) are monotone in |w-c|, so the fl-distance
// argmin is attained at a sorted neighbor; exact fl-ties resolved by original
// index (numpy argmin first-index rule) on a nearly-never-taken uniform branch.

#define VQ_K 64
#define TPB  256
#define SEG  4                 // float4 segments per thread
#define BLK_F4 (TPB * SEG)     // float4 groups per block (1024 -> 4096 elems)

__global__ __launch_bounds__(TPB) void vq_kernel(
    const float* __restrict__ w,
    const float* __restrict__ cb,
    float* __restrict__ out,
    int n4)                    // number of float4 groups
{
    __shared__ float C[VQ_K];
    __shared__ float S[VQ_K + 2];   // [0]=+inf, [1..64]=sorted, [65]=+inf
    __shared__ int   SI[VQ_K + 2];  // original indices (sentinels huge)
    __shared__ float T2r[64];       // level s=2 pivots, 4 replicas of 16
    __shared__ float T1r[68];       // level s=1 pivots, 2 replicas of 34 (33 used)

    const int tid = threadIdx.x;

    if (tid < VQ_K) C[tid] = cb[tid];
    __syncthreads();
    if (tid < VQ_K) {
        const float c = C[tid];
        int rank = 0;
#pragma unroll
        for (int j = 0; j < VQ_K; ++j) {
            const float cj = C[j];
            rank += (cj < c || (cj == c && j < tid)) ? 1 : 0;   // stable rank
        }
        S[rank + 1] = c;
        SI[rank + 1] = tid;
    }
    if (tid == TPB - 1) {
        S[0] = __builtin_inff();          SI[0] = 1 << 30;
        S[VQ_K + 1] = __builtin_inff();   SI[VQ_K + 1] = 1 << 30;
    }
    __syncthreads();
    if (tid < 64) T2r[tid] = S[4 * (tid & 15) + 2];
    if (tid < 34) T1r[tid]      = (tid < 33) ? S[2 * tid + 1] : 0.0f;
    else if (tid < 68) { int i = tid - 34; T1r[tid] = (i < 33) ? S[2 * i + 1] : 0.0f; }
    __syncthreads();

    // Register pivots: levels s=32,16,8 and s=4 (broadcast LDS reads, no conflict).
    const float c32 = S[32];
    const float c16 = S[16], c48 = S[48];
    const float c8  = S[8],  c24 = S[24], c40 = S[40], c56 = S[56];
    const float c4  = S[4],  c12 = S[12], c20 = S[20], c28 = S[28];
    const float c36 = S[36], c44 = S[44], c52 = S[52], c60 = S[60];

    const int lane  = tid & 63;
    const int repl2 = lane & 48;          // (lane>>4)*16
    const int repl1 = (lane >> 5) * 34;   // 0 or 34

    const int base4 = blockIdx.x * BLK_F4 + tid;   // float4 index, segment 0
    float4 x[SEG];
    bool   ok[SEG];
#pragma unroll
    for (int s = 0; s < SEG; ++s) {
        const int i4 = base4 + s * TPB;
        ok[s] = (i4 < n4);
        if (ok[s]) x[s] = reinterpret_cast<const float4*>(w)[i4];
    }

#pragma unroll
    for (int s = 0; s < SEG; ++s) {
        if (!ok[s]) continue;
        float e[4] = {x[s].x, x[s].y, x[s].z, x[s].w};
        float r[4];
#pragma unroll
        for (int j = 0; j < 4; ++j) {
            const float wv = e[j];
            const bool b0 = (c32 <= wv);
            const float p1 = b0 ? c48 : c16;
            const bool b1 = (p1 <= wv);
            const float pa = b0 ? c56 : c24, pb = b0 ? c40 : c8;
            const float p2 = b1 ? pa : pb;
            const bool b2 = (p2 <= wv);
            // level s=4 from registers
            const float q0 = b0 ? c36 : c4;
            const float q1 = b0 ? c44 : c12;
            const float q2 = b0 ? c52 : c20;
            const float q3 = b0 ? c60 : c28;
            const float r0 = b1 ? q2 : q0;
            const float r1 = b1 ? q3 : q1;
            const float p3 = b2 ? r1 : r0;
            const bool b3 = (p3 <= wv);
            const int i2 = (b0 ? 8 : 0) + (b1 ? 4 : 0) + (b2 ? 2 : 0) + (b3 ? 1 : 0);
            // level s=2 (replicated table, ~2-way max)
            const float p4 = T2r[repl2 + i2];
            const bool b4 = (p4 <= wv);
            const int i1 = 2 * i2 + (b4 ? 1 : 0);
            // level s=1 (replicated table)
            const float p5 = T1r[repl1 + i1];
            const bool b5 = (p5 <= wv);
            const int pos = 2 * i1 + (b5 ? 1 : 0);   // = #codes <= wv, in [0,64]

            const float cl = S[pos], cr = S[pos + 1];
            const float dl = wv - cl, dr = wv - cr;
            const float dl2 = dl * dl, dr2 = dr * dr;
            float q = (dr2 < dl2) ? cr : cl;
            const bool tie = (dl2 == dr2);
            if (__any(tie)) {               // uniform branch, ~never taken
                if (tie) q = (SI[pos] < SI[pos + 1]) ? cl : cr;
            }
            r[j] = q;
        }
        const int i4 = base4 + s * TPB;
        reinterpret_cast<float4*>(out)[i4] = make_float4(r[0], r[1], r[2], r[3]);
    }
}

// Naive exact fallback for tail elements (n % 4 != 0).
__global__ void vq_tail_kernel(const float* __restrict__ w,
                               const float* __restrict__ cb,
                               float* __restrict__ out, int start, int n) {
    int i = start + blockIdx.x * blockDim.x + threadIdx.x;
    if (i >= n) return;
    float wx = w[i];
    float c0 = cb[0], d0 = wx - c0;
    float bd = d0 * d0, bv = c0;
#pragma unroll
    for (int k = 1; k < VQ_K; ++k) {
        float c = cb[k], d = wx - c, dd = d * d;
        bool lt = dd < bd;
        bd = lt ? dd : bd;
        bv = lt ? c : bv;
    }
    out[i] = bv;
}

extern "C" void kernel_launch(void* const* d_in, const int* in_sizes, int n_in,
                              void* d_out, int out_size, void* d_ws, size_t ws_size,
                              hipStream_t stream) {
    const float* w  = (const float*)d_in[0];
    const float* cb = (const float*)d_in[1];
    float* out = (float*)d_out;
    const int n  = in_sizes[0];
    const int n4 = n / 4;

    if (n4 > 0) {
        const int grid = (n4 + BLK_F4 - 1) / BLK_F4;
        vq_kernel<<<grid, TPB, 0, stream>>>(w, cb, out, n4);
    }
    if (n4 * 4 < n) {
        vq_tail_kernel<<<1, 64, 0, stream>>>(w, cb, out, n4 * 4, n);
    }
}